// Round 18
// baseline (262.383 us; speedup 1.0000x reference)
//
#include <hip/hip_runtime.h>
#include <hip/hip_bf16.h>
#include <math.h>

typedef __bf16 bf16x8 __attribute__((ext_vector_type(8)));
typedef float f32x4 __attribute__((ext_vector_type(4)));
typedef unsigned short u16x4 __attribute__((ext_vector_type(4)));

#define AS1P const __attribute__((address_space(1))) void*
#define AS3P __attribute__((address_space(3))) void*

__device__ __forceinline__ float b2f(unsigned short h) {
    unsigned int u = ((unsigned int)h) << 16;
    return __builtin_bit_cast(float, u);
}
__device__ __forceinline__ unsigned short f2b(float f) {
    unsigned int u = __builtin_bit_cast(unsigned int, f);
    u += 0x7FFFu + ((u >> 16) & 1u);
    return (unsigned short)(u >> 16);
}
__device__ __forceinline__ float silu(float c) {
    return c * __builtin_amdgcn_rcpf(1.0f + __expf(-c));
}

// ================= fused pre-pass: convT(uv_W) | convT(o_W) | LayerNorm
__global__ __launch_bounds__(256) void k_pre(const float* __restrict__ uv_W,
                                             unsigned short* __restrict__ uvWT,
                                             const float* __restrict__ o_W,
                                             unsigned short* __restrict__ oWT,
                                             const float* __restrict__ x,
                                             const float* __restrict__ g,
                                             const float* __restrict__ bia,
                                             unsigned short* __restrict__ xn) {
    __shared__ float tile[32][33];
    __shared__ float ss[4], sq[4];
    int b = blockIdx.x;
    int t = threadIdx.x;
    if (b < 3552) {
        const float* src;
        unsigned short* dst;
        int R, C, bx, by;
        if (b < 2400) {
            src = uv_W; dst = uvWT; R = 768; C = 3200;
            bx = b % 100; by = b / 100;
        } else {
            int b2 = b - 2400;
            src = o_W; dst = oWT; R = 1536; C = 768;
            bx = b2 % 24; by = b2 / 24;
        }
        int tx = t & 31, ty = t >> 5;
        int r0 = by << 5, c0 = bx << 5;
#pragma unroll
        for (int i = 0; i < 4; ++i)
            tile[ty + 8 * i][tx] = src[(long long)(r0 + ty + 8 * i) * C + c0 + tx];
        __syncthreads();
#pragma unroll
        for (int i = 0; i < 4; ++i)
            dst[(long long)(c0 + ty + 8 * i) * R + r0 + tx] = f2b(tile[tx][ty + 8 * i]);
        return;
    }
    int row = b - 3552;
    const float* xr = x + (long long)row * 768;
    float v0 = xr[t], v1 = xr[t + 256], v2 = xr[t + 512];
    float s = v0 + v1 + v2;
    float q = v0 * v0 + v1 * v1 + v2 * v2;
#pragma unroll
    for (int off = 32; off > 0; off >>= 1) {
        s += __shfl_xor(s, off);
        q += __shfl_xor(q, off);
    }
    int w = t >> 6;
    if ((t & 63) == 0) { ss[w] = s; sq[w] = q; }
    __syncthreads();
    float S_ = ss[0] + ss[1] + ss[2] + ss[3];
    float Q_ = sq[0] + sq[1] + sq[2] + sq[3];
    float mu = S_ * (1.0f / 768.0f);
    float var = Q_ * (1.0f / 768.0f) - mu * mu;
    float rs = rsqrtf(var + 1e-5f);
    unsigned short* xo = xn + (long long)row * 768;
    xo[t]       = f2b((v0 - mu) * rs * g[t]       + bia[t]);
    xo[t + 256] = f2b((v1 - mu) * rs * g[t + 256] + bia[t + 256]);
    xo[t + 512] = f2b((v2 - mu) * rs * g[t + 512] + bia[t + 512]);
}

// ================= bS + RoPE fused: 64x128 tile, K=768, grid 256 = 1 round.
__global__ __launch_bounds__(256) void k_bs(const unsigned short* __restrict__ A,
                                            const unsigned short* __restrict__ B,
                                            const float* __restrict__ bias,
                                            const float* __restrict__ gqk,
                                            const float* __restrict__ bqk,
                                            unsigned short* __restrict__ q,
                                            unsigned short* __restrict__ k) {
    __shared__ __align__(16) unsigned short sh[12288];
    unsigned short* As_ = sh;
    unsigned short* Bs_ = sh + 4096;
    int t = threadIdx.x;
    int w = t >> 6, lane = t & 63;
    int wr = w >> 1, wc = w & 1;
    int by = blockIdx.x;
    const unsigned short* Ab = A + (long long)by * 64 * 768;

    f32x4 acc[2][4];
#pragma unroll
    for (int m = 0; m < 2; ++m)
#pragma unroll
        for (int n = 0; n < 4; ++n) acc[m][n] = (f32x4){0.f, 0.f, 0.f, 0.f};

    int rowA = (w << 3) + (lane >> 3);
    int colA = (lane & 7) << 3;

    for (int k0 = 0; k0 < 768; k0 += 64) {
#pragma unroll
        for (int i = 0; i < 2; ++i) {
            int r = (i << 5) + rowA;
            __builtin_amdgcn_global_load_lds(
                (AS1P)(Ab + (long long)r * 768 + k0 + colA),
                (AS3P)(&As_[(i << 11) + (w << 9)]), 16, 0, 0);
        }
#pragma unroll
        for (int i = 0; i < 4; ++i) {
            int r = (i << 5) + rowA;
            __builtin_amdgcn_global_load_lds(
                (AS1P)(B + (long long)r * 768 + k0 + colA),
                (AS3P)(&Bs_[(i << 11) + (w << 9)]), 16, 0, 0);
        }
        __syncthreads();
#pragma unroll
        for (int ks = 0; ks < 2; ++ks) {
            bf16x8 af[2], bfr[4];
#pragma unroll
            for (int m = 0; m < 2; ++m)
                af[m] = *(const bf16x8*)&As_[((wr << 5) + (m << 4) + (lane & 15)) * 64 +
                                             (ks << 5) + ((lane >> 4) << 3)];
#pragma unroll
            for (int n = 0; n < 4; ++n)
                bfr[n] = *(const bf16x8*)&Bs_[((wc << 6) + (n << 4) + (lane & 15)) * 64 +
                                              (ks << 5) + ((lane >> 4) << 3)];
#pragma unroll
            for (int m = 0; m < 2; ++m)
#pragma unroll
                for (int n = 0; n < 4; ++n)
                    acc[m][n] = __builtin_amdgcn_mfma_f32_16x16x32_bf16(bfr[n], af[m],
                                                                        acc[m][n], 0, 0, 0);
        }
        __syncthreads();
    }

    unsigned short* tile = sh;
    int c15 = lane & 15, qq = lane >> 4;
    int lrowb = (wr << 5) + c15;
    int colb = (wc << 6) + (qq << 2);
#pragma unroll
    for (int m = 0; m < 2; ++m) {
#pragma unroll
        for (int n = 0; n < 4; ++n) {
            int lrow = lrowb + (m << 4);
            int gcol = colb + (n << 4);
            f32x4 a = acc[m][n];
            u16x4 o;
#pragma unroll
            for (int i = 0; i < 4; ++i)
                o[i] = f2b(silu(a[i] + bias[gcol + i]));
            *(u16x4*)(tile + lrow * 128 + gcol) = o;
        }
    }
    __syncthreads();

    int s = t & 127, rgrp = t >> 7;
    int pr = s ^ 64;
    float gq0 = gqk[s], bq0 = bqk[s];
    float gqp = gqk[pr], bqp = bqk[pr];
    float gk0 = gqk[128 + s], bk0 = bqk[128 + s];
    float gkp = gqk[128 + pr], bkp = bqk[128 + pr];
    float invf = __expf((float)(s & 63) * -0.14391156831f);
    float sign = (s < 64) ? -1.0f : 1.0f;
#pragma unroll 4
    for (int rr = 0; rr < 32; ++rr) {
        int lrow = rgrp * 32 + rr;
        int grow = (by << 6) + lrow;
        int l = grow & 511;
        float th = (float)l * invf;
        float sn, cs;
        __sincosf(th, &sn, &cs);
        float b0 = b2f(tile[lrow * 128 + s]);
        float bp = b2f(tile[lrow * 128 + pr]);
        q[(long long)grow * 128 + s] = f2b((b0 * gq0 + bq0) * cs + sign * (bp * gqp + bqp) * sn);
        k[(long long)grow * 128 + s] = f2b((b0 * gk0 + bk0) * cs + sign * (bp * gkp + bkp) * sn);
    }
}

// ================= 256xN 8-phase kernel — persistent-block variant.
// Each block owns TPB tiles (stride = gridDim); tile->(bx,by,bz) mapping is the
// SAME chunked XCD swizzle as the multi-round launches (identical locality).
// Next tile's prologue is issued BEFORE the current epilogue (DMA hides under
// silu/stores). Epilogue stores inflate vmcnt counts -> waits only get stricter.
__device__ __forceinline__ bf16x8 ldsread(const unsigned short* p) {
    bf16x8 r;
    unsigned int off =
        (unsigned int)(unsigned long long)(__attribute__((address_space(3))) const void*)p;
    asm volatile("ds_read_b128 %0, %1" : "=v"(r) : "v"(off));
    return r;
}
__device__ __forceinline__ void stage_half(const unsigned short* __restrict__ g, int ldk,
                                           unsigned short* lds, int t) {
#pragma unroll
    for (int i = 0; i < 2; ++i) {
        int slot = t + (i << 9);
        int row = slot >> 2;
        int gs = (slot & 3) ^ ((slot >> 3) & 3);
        __builtin_amdgcn_global_load_lds(
            (AS1P)(g + (long long)row * ldk + (gs << 3)),
            (AS3P)(lds + slot * 8), 16, 0, 0);
    }
}

template <int K>
__device__ __forceinline__ void prologue8(const unsigned short* __restrict__ Ab,
                                          const unsigned short* __restrict__ Bb,
                                          unsigned short* As, unsigned short* Bs, int tid) {
    stage_half(Ab, K, As + 0, tid);
    stage_half(Bb, K, Bs + 0, tid);
    stage_half(Ab + 32, K, As + 8192, tid);
    stage_half(Bb + 32, K, Bs + 8192, tid);
    stage_half(Ab + 64, K, As + 16384, tid);
    stage_half(Bb + 64, K, Bs + 16384, tid);
}

template <bool SWAP, int NT, int NF>
__device__ __forceinline__ void body8(const unsigned short* __restrict__ Ab,
                                      const unsigned short* __restrict__ Bb,
                                      unsigned short* As, unsigned short* Bs,
                                      f32x4 (&acc)[8][NF], int tid,
                                      int wr, int wc, int c15, int gq) {
    constexpr int K = NT * 64;
    asm volatile("s_waitcnt vmcnt(8)" ::: "memory");
    __builtin_amdgcn_s_barrier();

    bf16x8 bfr[NF], af[4];
    for (int t = 0; t < NT; ++t) {
        const int b = t & 1;
        const unsigned short* A0 = As + b * 16384;
        const unsigned short* B0 = Bs + b * 16384;
#pragma unroll
        for (int p = 0; p < 4; ++p) {
            const int ks = p >> 1, mh = p & 1;
            const unsigned short* At = A0 + ks * 8192;
            const unsigned short* Bt = B0 + ks * 8192;
            if (mh == 0) {
#pragma unroll
                for (int n = 0; n < NF; ++n)
                    bfr[n] = ldsread(Bt + (wc * (NF * 16) + n * 16 + c15) * 32 + gq * 8);
            }
#pragma unroll
            for (int j = 0; j < 4; ++j)
                af[j] = ldsread(At + (wr * 128 + (mh * 4 + j) * 16 + c15) * 32 + gq * 8);
            if (p == 0) {
                if (t + 1 < NT)
                    stage_half(Ab + (t + 1) * 64 + 32, K,
                               As + (((t + 1) & 1) * 2 + 1) * 8192, tid);
            } else if (p == 1) {
                if (t + 1 < NT)
                    stage_half(Bb + (t + 1) * 64 + 32, K,
                               Bs + (((t + 1) & 1) * 2 + 1) * 8192, tid);
            } else if (p == 2) {
                if (t + 2 < NT)
                    stage_half(Ab + (t + 2) * 64, K, As + (b * 2) * 8192, tid);
            } else {
                if (t + 2 < NT)
                    stage_half(Bb + (t + 2) * 64, K, Bs + (b * 2) * 8192, tid);
            }
            __builtin_amdgcn_s_barrier();
            asm volatile("s_waitcnt lgkmcnt(0)" ::: "memory");
            __builtin_amdgcn_sched_barrier(0);
            __builtin_amdgcn_s_setprio(1);
#pragma unroll
            for (int j = 0; j < 4; ++j)
#pragma unroll
                for (int n = 0; n < NF; ++n) {
                    if constexpr (SWAP)
                        acc[mh * 4 + j][n] = __builtin_amdgcn_mfma_f32_16x16x32_bf16(
                            bfr[n], af[j], acc[mh * 4 + j][n], 0, 0, 0);
                    else
                        acc[mh * 4 + j][n] = __builtin_amdgcn_mfma_f32_16x16x32_bf16(
                            af[j], bfr[n], acc[mh * 4 + j][n], 0, 0, 0);
                }
            __builtin_amdgcn_s_setprio(0);
            if (p == 1) {
                if (t < NT - 1)
                    asm volatile("s_waitcnt vmcnt(8)" ::: "memory");
                else
                    asm volatile("s_waitcnt vmcnt(0)" ::: "memory");
            } else if (p == 3) {
                if (t < NT - 2)
                    asm volatile("s_waitcnt vmcnt(8)" ::: "memory");
                else if (t == NT - 2)
                    asm volatile("s_waitcnt vmcnt(4)" ::: "memory");
            }
            __builtin_amdgcn_sched_barrier(0);
            __builtin_amdgcn_s_barrier();
        }
    }
}

// EPI: 10 = UV (u bx<6 | vT bx 6-11, NF=4)   2 = gated(PV*u, NF=3)
//      3 = out f32(+o_b+x, NF=3)   1 = P relu^2 (QK, NF=2)
template <int EPI, int TX, int TY, int TZ, int TPB, int NT, int NF>
__global__ __launch_bounds__(512, 2) void k8(const unsigned short* __restrict__ A,
                                             const unsigned short* __restrict__ B,
                                             long long strideA, long long strideB,
                                             void* p0, void* p1, void* p2,
                                             const void* p3) {
    constexpr int K = NT * 64;
    constexpr int NTILES = TX * TY * TZ;
    constexpr int NBLK = NTILES / TPB;
    __shared__ __align__(16) unsigned short As[2][2][256 * 32];
    __shared__ __align__(16) unsigned short Bs[2][2][256 * 32];
    int tid = threadIdx.x;
    int w = tid >> 6, lane = tid & 63;
    int wr = w >> 2, wc = w & 3;
    int c15 = lane & 15, qq = lane >> 4;
    int gq = qq ^ ((c15 >> 1) & 3);
    int pid = blockIdx.x;

    int bx, by, bz;
    auto decomp = [&](int f) {
        int s = (f & 7) * (NTILES >> 3) + (f >> 3);
        bx = s % TX;
        by = (s / TX) % TY;
        bz = s / (TX * TY);
    };
    decomp(pid);
    const unsigned short* Ab = A + bz * strideA + (long long)by * 256 * K;
    const unsigned short* Bb = B + bz * strideB + (long long)bx * (NF * 64) * K;
    prologue8<K>(Ab, Bb, &As[0][0][0], &Bs[0][0][0], tid);

    for (int j = 0; j < TPB; ++j) {
        f32x4 acc[8][NF];
#pragma unroll
        for (int m = 0; m < 8; ++m)
#pragma unroll
            for (int n = 0; n < NF; ++n) acc[m][n] = (f32x4){0.f, 0.f, 0.f, 0.f};

        bool swapped = true;
        if constexpr (EPI == 10) {
            swapped = (bx < 6);
            if (swapped)
                body8<true, NT, NF>(Ab, Bb, &As[0][0][0], &Bs[0][0][0], acc, tid, wr, wc, c15, gq);
            else
                body8<false, NT, NF>(Ab, Bb, &As[0][0][0], &Bs[0][0][0], acc, tid, wr, wc, c15, gq);
        } else {
            body8<true, NT, NF>(Ab, Bb, &As[0][0][0], &Bs[0][0][0], acc, tid, wr, wc, c15, gq);
        }
        int ebx = bx, eby = by, ebz = bz;
        if (j + 1 < TPB) {   // issue next tile's prologue before the epilogue
            decomp(pid + (j + 1) * NBLK);
            Ab = A + bz * strideA + (long long)by * 256 * K;
            Bb = B + bz * strideB + (long long)bx * (NF * 64) * K;
            prologue8<K>(Ab, Bb, &As[0][0][0], &Bs[0][0][0], tid);
        }

        // ---- epilogue for tile (ebx, eby, ebz)
        if constexpr (EPI == 10) {
            if (swapped) {
                int rowb = eby * 256 + wr * 128 + c15;
                int colb = ebx * 256 + wc * 64 + (qq << 2);
#pragma unroll
                for (int m = 0; m < 8; ++m) {
#pragma unroll
                    for (int n = 0; n < NF; ++n) {
                        int R = rowb + m * 16;
                        int C = colb + n * 16;
                        f32x4 a = acc[m][n];
                        f32x4 bb = *(const f32x4*)((const float*)p3 + C);
                        u16x4 o;
#pragma unroll
                        for (int i = 0; i < 4; ++i) o[i] = f2b(silu(a[i] + bb[i]));
                        *(u16x4*)((unsigned short*)p0 + (long long)R * 1536 + C) = o;
                    }
                }
            } else {
                int rowb = eby * 256 + wr * 128 + (qq << 2);
                int colb = ebx * 256 + wc * 64 + c15;
#pragma unroll
                for (int m = 0; m < 8; ++m) {
#pragma unroll
                    for (int n = 0; n < NF; ++n) {
                        int R = rowb + m * 16;
                        int C = colb + n * 16;
                        float bias = ((const float*)p3)[C];
                        f32x4 a = acc[m][n];
                        u16x4 o;
#pragma unroll
                        for (int i = 0; i < 4; ++i) o[i] = f2b(silu(a[i] + bias));
                        int bb2 = R >> 9, mm = R & 511;
                        *(u16x4*)((unsigned short*)p1 +
                                  ((long long)bb2 * 1600 + (C - 1536)) * 512 + mm) = o;
                    }
                }
            }
        } else if constexpr (EPI == 1) {
            const float* wrel = (const float*)p1;
            int rowb = eby * 256 + wr * 128 + c15;
            int colb = ebx * (NF * 64) + wc * (NF * 16) + (qq << 2);
#pragma unroll
            for (int m = 0; m < 8; ++m) {
#pragma unroll
                for (int n = 0; n < NF; ++n) {
                    int R = rowb + m * 16;
                    int C = colb + n * 16;
                    f32x4 a = acc[m][n];
                    int base = C - R + 511;
                    u16x4 o;
#pragma unroll
                    for (int i = 0; i < 4; ++i) {
                        float val = a[i] * (1.0f / 512.0f) + wrel[base + i];
                        val = fmaxf(val, 0.0f);
                        o[i] = f2b(val * val);
                    }
                    *(u16x4*)((unsigned short*)p0 +
                              ((long long)(ebz * 512 + R)) * 512 + C) = o;
                }
            }
        } else if constexpr (EPI == 2) {
            int rowb = eby * 256 + wr * 128 + c15;
            int colb = ebx * (NF * 64) + wc * (NF * 16) + (qq << 2);
#pragma unroll
            for (int m = 0; m < 8; ++m) {
#pragma unroll
                for (int n = 0; n < NF; ++n) {
                    int R = rowb + m * 16;
                    int C = colb + n * 16;
                    f32x4 a = acc[m][n];
                    long long idx = ((long long)(ebz * 512 + R)) * 1536 + C;
                    u16x4 uu = *(const u16x4*)((const unsigned short*)p1 + idx);
                    u16x4 o;
#pragma unroll
                    for (int i = 0; i < 4; ++i) o[i] = f2b(a[i] * b2f(uu[i]));
                    *(u16x4*)((unsigned short*)p0 + idx) = o;
                }
            }
        } else {
            int rowb = eby * 256 + wr * 128 + c15;
            int colb = ebx * (NF * 64) + wc * (NF * 16) + (qq << 2);
#pragma unroll
            for (int m = 0; m < 8; ++m) {
#pragma unroll
                for (int n = 0; n < NF; ++n) {
                    int R = rowb + m * 16;
                    int C = colb + n * 16;
                    f32x4 a = acc[m][n];
                    long long idx = (long long)R * 768 + C;
                    f32x4 xv = *(const f32x4*)((const float*)p2 + idx);
                    f32x4 ob = *(const f32x4*)((const float*)p1 + C);
                    f32x4 o;
#pragma unroll
                    for (int i = 0; i < 4; ++i) o[i] = a[i] + ob[i] + xv[i];
                    *(f32x4*)((float*)p0 + idx) = o;
                }
            }
        }
    }
}

extern "C" void kernel_launch(void* const* d_in, const int* in_sizes, int n_in,
                              void* d_out, int out_size, void* d_ws, size_t ws_size,
                              hipStream_t stream) {
    const float* x     = (const float*)d_in[0];
    const float* ln_g  = (const float*)d_in[1];
    const float* ln_b  = (const float*)d_in[2];
    const float* uv_W  = (const float*)d_in[3];
    const float* uv_b  = (const float*)d_in[4];
    const float* g_qk  = (const float*)d_in[5];
    const float* b_qk  = (const float*)d_in[6];
    const float* w_rel = (const float*)d_in[7];
    const float* o_W   = (const float*)d_in[8];
    const float* o_b   = (const float*)d_in[9];
    float* out = (float*)d_out;

    char* ws = (char*)d_ws;
    size_t off = 0;
    auto alloc = [&](size_t bytes) {
        void* p = ws + off;
        off += (bytes + 255) & ~(size_t)255;
        return p;
    };
    unsigned short* uvWT = (unsigned short*)alloc(3200ll * 768 * 2);
    unsigned short* oWT  = (unsigned short*)alloc(832ll * 1536 * 2);   // 768 + 64 pad rows
    unsigned short* xn   = (unsigned short*)alloc(16384ll * 768 * 2);
    unsigned short* u    = (unsigned short*)alloc(16384ll * 1536 * 2);
    unsigned short* vT   = (unsigned short*)alloc(32ll * 1600 * 512 * 2);  // +64 pad/batch
    unsigned short* q    = (unsigned short*)alloc(32ll * 512 * 128 * 2);
    unsigned short* k    = (unsigned short*)alloc((32ll * 512 + 128) * 128 * 2);  // +128 pad
    unsigned short* P     = xn;  // alias: xn dead after UV+bS kernels
    unsigned short* gated = u;   // alias: same-thread read-then-write

    // fused convT(uv_W) + convT(o_W) + LayerNorm
    k_pre<<<19936, 256, 0, stream>>>(uv_W, uvWT, o_W, oWT, x, ln_g, ln_b, xn);
    // UV: u | vT (768 tiles, persistent 256 blocks x 3 tiles)
    k8<10, 12, 64, 1, 3, 12, 4><<<256, 512, 0, stream>>>(
        xn, uvWT, 0, 0, (void*)u, (void*)vT, nullptr, (const void*)uv_b);
    // bS + rope fused: 256 blocks = 1 round -> q,k
    k_bs<<<256, 256, 0, stream>>>(xn, uvWT + 3072ll * 768, uv_b + 3072,
                                  g_qk, b_qk, q, k);
    // QK^T -> P: 256 tiles, 1 tile/block
    k8<1, 4, 2, 32, 1, 2, 2><<<256, 512, 0, stream>>>(
        q, k, 512ll * 128, 512ll * 128, (void*)P, (void*)w_rel, nullptr, nullptr);
    // PV gated by u: 512 tiles, persistent 256 blocks x 2 tiles
    k8<2, 8, 2, 32, 2, 8, 3><<<256, 512, 0, stream>>>(
        P, vT, 512ll * 512, 1600ll * 512, (void*)gated, (void*)u, nullptr, nullptr);
    // out: 256 tiles, 1 tile/block
    k8<3, 4, 64, 1, 1, 24, 3><<<256, 512, 0, stream>>>(
        gated, oWT, 0, 0, (void*)out, (void*)o_b, (void*)x, nullptr);
}

// Round 19
// 259.404 us; speedup vs baseline: 1.0115x; 1.0115x over previous
//
#include <hip/hip_runtime.h>
#include <hip/hip_bf16.h>
#include <math.h>

typedef __bf16 bf16x8 __attribute__((ext_vector_type(8)));
typedef float f32x4 __attribute__((ext_vector_type(4)));
typedef unsigned short u16x4 __attribute__((ext_vector_type(4)));

#define AS1P const __attribute__((address_space(1))) void*
#define AS3P __attribute__((address_space(3))) void*

__device__ __forceinline__ float b2f(unsigned short h) {
    unsigned int u = ((unsigned int)h) << 16;
    return __builtin_bit_cast(float, u);
}
__device__ __forceinline__ unsigned short f2b(float f) {
    unsigned int u = __builtin_bit_cast(unsigned int, f);
    u += 0x7FFFu + ((u >> 16) & 1u);
    return (unsigned short)(u >> 16);
}
__device__ __forceinline__ float silu(float c) {
    return c * __builtin_amdgcn_rcpf(1.0f + __expf(-c));
}

// ================= fused pre-pass: convT(uv_W) | convT(o_W) | LayerNorm
__global__ __launch_bounds__(256) void k_pre(const float* __restrict__ uv_W,
                                             unsigned short* __restrict__ uvWT,
                                             const float* __restrict__ o_W,
                                             unsigned short* __restrict__ oWT,
                                             const float* __restrict__ x,
                                             const float* __restrict__ g,
                                             const float* __restrict__ bia,
                                             unsigned short* __restrict__ xn) {
    __shared__ float tile[32][33];
    __shared__ float ss[4], sq[4];
    int b = blockIdx.x;
    int t = threadIdx.x;
    if (b < 3552) {
        const float* src;
        unsigned short* dst;
        int R, C, bx, by;
        if (b < 2400) {
            src = uv_W; dst = uvWT; R = 768; C = 3200;
            bx = b % 100; by = b / 100;
        } else {
            int b2 = b - 2400;
            src = o_W; dst = oWT; R = 1536; C = 768;
            bx = b2 % 24; by = b2 / 24;
        }
        int tx = t & 31, ty = t >> 5;
        int r0 = by << 5, c0 = bx << 5;
#pragma unroll
        for (int i = 0; i < 4; ++i)
            tile[ty + 8 * i][tx] = src[(long long)(r0 + ty + 8 * i) * C + c0 + tx];
        __syncthreads();
#pragma unroll
        for (int i = 0; i < 4; ++i)
            dst[(long long)(c0 + ty + 8 * i) * R + r0 + tx] = f2b(tile[tx][ty + 8 * i]);
        return;
    }
    int row = b - 3552;
    const float* xr = x + (long long)row * 768;
    float v0 = xr[t], v1 = xr[t + 256], v2 = xr[t + 512];
    float s = v0 + v1 + v2;
    float q = v0 * v0 + v1 * v1 + v2 * v2;
#pragma unroll
    for (int off = 32; off > 0; off >>= 1) {
        s += __shfl_xor(s, off);
        q += __shfl_xor(q, off);
    }
    int w = t >> 6;
    if ((t & 63) == 0) { ss[w] = s; sq[w] = q; }
    __syncthreads();
    float S_ = ss[0] + ss[1] + ss[2] + ss[3];
    float Q_ = sq[0] + sq[1] + sq[2] + sq[3];
    float mu = S_ * (1.0f / 768.0f);
    float var = Q_ * (1.0f / 768.0f) - mu * mu;
    float rs = rsqrtf(var + 1e-5f);
    unsigned short* xo = xn + (long long)row * 768;
    xo[t]       = f2b((v0 - mu) * rs * g[t]       + bia[t]);
    xo[t + 256] = f2b((v1 - mu) * rs * g[t + 256] + bia[t + 256]);
    xo[t + 512] = f2b((v2 - mu) * rs * g[t + 512] + bia[t + 512]);
}

// ================= bS + RoPE fused: 64x128 tile, K=768, grid 256 = 1 round.
// Computes silu(xn @ W3^T + b3) into LDS, then applies rope in-block -> q,k.
__global__ __launch_bounds__(256) void k_bs(const unsigned short* __restrict__ A,
                                            const unsigned short* __restrict__ B,
                                            const float* __restrict__ bias,
                                            const float* __restrict__ gqk,
                                            const float* __restrict__ bqk,
                                            unsigned short* __restrict__ q,
                                            unsigned short* __restrict__ k) {
    __shared__ __align__(16) unsigned short sh[12288];  // staging 24KB; tile reuses
    unsigned short* As_ = sh;          // 64x64
    unsigned short* Bs_ = sh + 4096;   // 128x64
    int t = threadIdx.x;
    int w = t >> 6, lane = t & 63;
    int wr = w >> 1, wc = w & 1;
    int by = blockIdx.x;
    const unsigned short* Ab = A + (long long)by * 64 * 768;

    f32x4 acc[2][4];
#pragma unroll
    for (int m = 0; m < 2; ++m)
#pragma unroll
        for (int n = 0; n < 4; ++n) acc[m][n] = (f32x4){0.f, 0.f, 0.f, 0.f};

    int rowA = (w << 3) + (lane >> 3);
    int colA = (lane & 7) << 3;

    for (int k0 = 0; k0 < 768; k0 += 64) {
#pragma unroll
        for (int i = 0; i < 2; ++i) {
            int r = (i << 5) + rowA;
            __builtin_amdgcn_global_load_lds(
                (AS1P)(Ab + (long long)r * 768 + k0 + colA),
                (AS3P)(&As_[(i << 11) + (w << 9)]), 16, 0, 0);
        }
#pragma unroll
        for (int i = 0; i < 4; ++i) {
            int r = (i << 5) + rowA;
            __builtin_amdgcn_global_load_lds(
                (AS1P)(B + (long long)r * 768 + k0 + colA),
                (AS3P)(&Bs_[(i << 11) + (w << 9)]), 16, 0, 0);
        }
        __syncthreads();
#pragma unroll
        for (int ks = 0; ks < 2; ++ks) {
            bf16x8 af[2], bfr[4];
#pragma unroll
            for (int m = 0; m < 2; ++m)
                af[m] = *(const bf16x8*)&As_[((wr << 5) + (m << 4) + (lane & 15)) * 64 +
                                             (ks << 5) + ((lane >> 4) << 3)];
#pragma unroll
            for (int n = 0; n < 4; ++n)
                bfr[n] = *(const bf16x8*)&Bs_[((wc << 6) + (n << 4) + (lane & 15)) * 64 +
                                              (ks << 5) + ((lane >> 4) << 3)];
#pragma unroll
            for (int m = 0; m < 2; ++m)
#pragma unroll
                for (int n = 0; n < 4; ++n)
                    acc[m][n] = __builtin_amdgcn_mfma_f32_16x16x32_bf16(bfr[n], af[m],
                                                                        acc[m][n], 0, 0, 0);
        }
        __syncthreads();
    }

    // epilogue: silu(acc + bias) -> LDS tile [64][128] (staging region dead)
    unsigned short* tile = sh;
    int c15 = lane & 15, qq = lane >> 4;
    int lrowb = (wr << 5) + c15;
    int colb = (wc << 6) + (qq << 2);
#pragma unroll
    for (int m = 0; m < 2; ++m) {
#pragma unroll
        for (int n = 0; n < 4; ++n) {
            int lrow = lrowb + (m << 4);
            int gcol = colb + (n << 4);
            f32x4 a = acc[m][n];
            u16x4 o;
#pragma unroll
            for (int i = 0; i < 4; ++i)
                o[i] = f2b(silu(a[i] + bias[gcol + i]));
            *(u16x4*)(tile + lrow * 128 + gcol) = o;
        }
    }
    __syncthreads();

    // rope: each thread owns col s for 32 rows
    int s = t & 127, rgrp = t >> 7;
    int pr = s ^ 64;
    float gq0 = gqk[s], bq0 = bqk[s];
    float gqp = gqk[pr], bqp = bqk[pr];
    float gk0 = gqk[128 + s], bk0 = bqk[128 + s];
    float gkp = gqk[128 + pr], bkp = bqk[128 + pr];
    float invf = __expf((float)(s & 63) * -0.14391156831f);
    float sign = (s < 64) ? -1.0f : 1.0f;
#pragma unroll 4
    for (int rr = 0; rr < 32; ++rr) {
        int lrow = rgrp * 32 + rr;
        int grow = (by << 6) + lrow;
        int l = grow & 511;
        float th = (float)l * invf;
        float sn, cs;
        __sincosf(th, &sn, &cs);
        float b0 = b2f(tile[lrow * 128 + s]);
        float bp = b2f(tile[lrow * 128 + pr]);
        q[(long long)grow * 128 + s] = f2b((b0 * gq0 + bq0) * cs + sign * (bp * gqp + bqp) * sn);
        k[(long long)grow * 128 + s] = f2b((b0 * gk0 + bk0) * cs + sign * (bp * gkp + bkp) * sn);
    }
}

// ================= 256xN 8-phase kernel (R7-verified ledger, N = NF*64).
__device__ __forceinline__ bf16x8 ldsread(const unsigned short* p) {
    bf16x8 r;
    unsigned int off =
        (unsigned int)(unsigned long long)(__attribute__((address_space(3))) const void*)p;
    asm volatile("ds_read_b128 %0, %1" : "=v"(r) : "v"(off));
    return r;
}
__device__ __forceinline__ void stage_half(const unsigned short* __restrict__ g, int ldk,
                                           unsigned short* lds, int t) {
#pragma unroll
    for (int i = 0; i < 2; ++i) {
        int slot = t + (i << 9);
        int row = slot >> 2;
        int gs = (slot & 3) ^ ((slot >> 3) & 3);
        __builtin_amdgcn_global_load_lds(
            (AS1P)(g + (long long)row * ldk + (gs << 3)),
            (AS3P)(lds + slot * 8), 16, 0, 0);
    }
}

template <bool SWAP, int NT, int NF>
__device__ __forceinline__ void kloop8(const unsigned short* __restrict__ Ab,
                                       const unsigned short* __restrict__ Bb,
                                       unsigned short* As, unsigned short* Bs,
                                       f32x4 (&acc)[8][NF], int tid,
                                       int wr, int wc, int c15, int qq, int gq) {
    constexpr int K = NT * 64;
    stage_half(Ab, K, As + 0, tid);
    stage_half(Bb, K, Bs + 0, tid);
    stage_half(Ab + 32, K, As + 8192, tid);
    stage_half(Bb + 32, K, Bs + 8192, tid);
    stage_half(Ab + 64, K, As + 16384, tid);
    stage_half(Bb + 64, K, Bs + 16384, tid);
    asm volatile("s_waitcnt vmcnt(8)" ::: "memory");
    __builtin_amdgcn_s_barrier();

    bf16x8 bfr[NF], af[4];
    for (int t = 0; t < NT; ++t) {
        const int b = t & 1;
        const unsigned short* A0 = As + b * 16384;
        const unsigned short* B0 = Bs + b * 16384;
#pragma unroll
        for (int p = 0; p < 4; ++p) {
            const int ks = p >> 1, mh = p & 1;
            const unsigned short* At = A0 + ks * 8192;
            const unsigned short* Bt = B0 + ks * 8192;
            if (mh == 0) {
#pragma unroll
                for (int n = 0; n < NF; ++n)
                    bfr[n] = ldsread(Bt + (wc * (NF * 16) + n * 16 + c15) * 32 + gq * 8);
            }
#pragma unroll
            for (int j = 0; j < 4; ++j)
                af[j] = ldsread(At + (wr * 128 + (mh * 4 + j) * 16 + c15) * 32 + gq * 8);
            if (p == 0) {
                if (t + 1 < NT)
                    stage_half(Ab + (t + 1) * 64 + 32, K,
                               As + (((t + 1) & 1) * 2 + 1) * 8192, tid);
            } else if (p == 1) {
                if (t + 1 < NT)
                    stage_half(Bb + (t + 1) * 64 + 32, K,
                               Bs + (((t + 1) & 1) * 2 + 1) * 8192, tid);
            } else if (p == 2) {
                if (t + 2 < NT)
                    stage_half(Ab + (t + 2) * 64, K, As + (b * 2) * 8192, tid);
            } else {
                if (t + 2 < NT)
                    stage_half(Bb + (t + 2) * 64, K, Bs + (b * 2) * 8192, tid);
            }
            __builtin_amdgcn_s_barrier();
            asm volatile("s_waitcnt lgkmcnt(0)" ::: "memory");
            __builtin_amdgcn_sched_barrier(0);
            __builtin_amdgcn_s_setprio(1);
#pragma unroll
            for (int j = 0; j < 4; ++j)
#pragma unroll
                for (int n = 0; n < NF; ++n) {
                    if constexpr (SWAP)
                        acc[mh * 4 + j][n] = __builtin_amdgcn_mfma_f32_16x16x32_bf16(
                            bfr[n], af[j], acc[mh * 4 + j][n], 0, 0, 0);
                    else
                        acc[mh * 4 + j][n] = __builtin_amdgcn_mfma_f32_16x16x32_bf16(
                            af[j], bfr[n], acc[mh * 4 + j][n], 0, 0, 0);
                }
            __builtin_amdgcn_s_setprio(0);
            if (p == 1) {
                if (t < NT - 1)
                    asm volatile("s_waitcnt vmcnt(8)" ::: "memory");
                else
                    asm volatile("s_waitcnt vmcnt(0)" ::: "memory");
            } else if (p == 3) {
                if (t < NT - 2)
                    asm volatile("s_waitcnt vmcnt(8)" ::: "memory");
                else if (t == NT - 2)
                    asm volatile("s_waitcnt vmcnt(4)" ::: "memory");
            }
            __builtin_amdgcn_sched_barrier(0);
            __builtin_amdgcn_s_barrier();
        }
    }
}

// EPI: 10 = UV (u bx<6 | vT bx 6-11, NF=4)   2 = gated(PV*u, NF=3)
//      3 = out f32(+o_b+x, NF=3)   1 = P relu^2 (QK, NF=2)
template <int EPI, int SWZ, int NT, int NF>
__global__ __launch_bounds__(512, 2) void k8(const unsigned short* __restrict__ A,
                                             const unsigned short* __restrict__ B,
                                             long long strideA, long long strideB,
                                             void* p0, void* p1, void* p2,
                                             const void* p3) {
    constexpr int K = NT * 64;
    __shared__ __align__(16) unsigned short As[2][2][256 * 32];
    __shared__ __align__(16) unsigned short Bs[2][2][256 * 32];
    int tid = threadIdx.x;
    int w = tid >> 6, lane = tid & 63;
    int wr = w >> 2, wc = w & 3;
    int c15 = lane & 15, qq = lane >> 4;
    int gq = qq ^ ((c15 >> 1) & 3);
    int bx = blockIdx.x, by = blockIdx.y, bz = blockIdx.z;
    if constexpr (SWZ == 1) {
        int gx = gridDim.x;
        int nb = gx * gridDim.y;
        int bid = by * gx + bx;
        int s = (bid & 7) * (nb >> 3) + (bid >> 3);
        bx = s % gx;
        by = s / gx;
    } else if constexpr (SWZ == 2) {
        int gx = gridDim.x, gy = gridDim.y;
        int nb = gx * gy * gridDim.z;
        int bid = (bz * gy + by) * gx + bx;
        int s = (bid & 7) * (nb >> 3) + (bid >> 3);
        bx = s % gx;
        by = (s / gx) % gy;
        bz = s / (gx * gy);
    }
    const unsigned short* Ab = A + bz * strideA + (long long)by * 256 * K;
    const unsigned short* Bb = B + bz * strideB + (long long)bx * (NF * 64) * K;

    f32x4 acc[8][NF];
#pragma unroll
    for (int m = 0; m < 8; ++m)
#pragma unroll
        for (int n = 0; n < NF; ++n) acc[m][n] = (f32x4){0.f, 0.f, 0.f, 0.f};

    bool swapped = true;
    if constexpr (EPI == 10) {
        swapped = (bx < 6);
        if (swapped)
            kloop8<true, NT, NF>(Ab, Bb, &As[0][0][0], &Bs[0][0][0], acc, tid, wr, wc, c15, qq, gq);
        else
            kloop8<false, NT, NF>(Ab, Bb, &As[0][0][0], &Bs[0][0][0], acc, tid, wr, wc, c15, qq, gq);
    } else {
        kloop8<true, NT, NF>(Ab, Bb, &As[0][0][0], &Bs[0][0][0], acc, tid, wr, wc, c15, qq, gq);
    }

    if constexpr (EPI == 10) {
        if (swapped) {
            int rowb = by * 256 + wr * 128 + c15;
            int colb = bx * 256 + wc * 64 + (qq << 2);
#pragma unroll
            for (int m = 0; m < 8; ++m) {
#pragma unroll
                for (int n = 0; n < NF; ++n) {
                    int R = rowb + m * 16;
                    int C = colb + n * 16;
                    f32x4 a = acc[m][n];
                    f32x4 bb = *(const f32x4*)((const float*)p3 + C);
                    u16x4 o;
#pragma unroll
                    for (int i = 0; i < 4; ++i) o[i] = f2b(silu(a[i] + bb[i]));
                    *(u16x4*)((unsigned short*)p0 + (long long)R * 1536 + C) = o;
                }
            }
        } else {
            int rowb = by * 256 + wr * 128 + (qq << 2);
            int colb = bx * 256 + wc * 64 + c15;
#pragma unroll
            for (int m = 0; m < 8; ++m) {
#pragma unroll
                for (int n = 0; n < NF; ++n) {
                    int R = rowb + m * 16;
                    int C = colb + n * 16;
                    float bias = ((const float*)p3)[C];
                    f32x4 a = acc[m][n];
                    u16x4 o;
#pragma unroll
                    for (int i = 0; i < 4; ++i) o[i] = f2b(silu(a[i] + bias));
                    int bb2 = R >> 9, mm = R & 511;
                    *(u16x4*)((unsigned short*)p1 +
                              ((long long)bb2 * 1600 + (C - 1536)) * 512 + mm) = o;
                }
            }
        }
    } else if constexpr (EPI == 1) {
        const float* wrel = (const float*)p1;
        int rowb = by * 256 + wr * 128 + c15;
        int colb = bx * (NF * 64) + wc * (NF * 16) + (qq << 2);
#pragma unroll
        for (int m = 0; m < 8; ++m) {
#pragma unroll
            for (int n = 0; n < NF; ++n) {
                int R = rowb + m * 16;
                int C = colb + n * 16;
                f32x4 a = acc[m][n];
                int base = C - R + 511;
                u16x4 o;
#pragma unroll
                for (int i = 0; i < 4; ++i) {
                    float val = a[i] * (1.0f / 512.0f) + wrel[base + i];
                    val = fmaxf(val, 0.0f);
                    o[i] = f2b(val * val);
                }
                *(u16x4*)((unsigned short*)p0 + ((long long)(bz * 512 + R)) * 512 + C) = o;
            }
        }
    } else if constexpr (EPI == 2) {
        int rowb = by * 256 + wr * 128 + c15;
        int colb = bx * (NF * 64) + wc * (NF * 16) + (qq << 2);
#pragma unroll
        for (int m = 0; m < 8; ++m) {
#pragma unroll
            for (int n = 0; n < NF; ++n) {
                int R = rowb + m * 16;
                int C = colb + n * 16;
                f32x4 a = acc[m][n];
                long long idx = ((long long)(bz * 512 + R)) * 1536 + C;
                u16x4 uu = *(const u16x4*)((const unsigned short*)p1 + idx);
                u16x4 o;
#pragma unroll
                for (int i = 0; i < 4; ++i) o[i] = f2b(a[i] * b2f(uu[i]));
                *(u16x4*)((unsigned short*)p0 + idx) = o;
            }
        }
    } else {
        int rowb = by * 256 + wr * 128 + c15;
        int colb = bx * (NF * 64) + wc * (NF * 16) + (qq << 2);
#pragma unroll
        for (int m = 0; m < 8; ++m) {
#pragma unroll
            for (int n = 0; n < NF; ++n) {
                int R = rowb + m * 16;
                int C = colb + n * 16;
                f32x4 a = acc[m][n];
                long long idx = (long long)R * 768 + C;
                f32x4 xv = *(const f32x4*)((const float*)p2 + idx);
                f32x4 ob = *(const f32x4*)((const float*)p1 + C);
                f32x4 o;
#pragma unroll
                for (int i = 0; i < 4; ++i) o[i] = a[i] + ob[i] + xv[i];
                *(f32x4*)((float*)p0 + idx) = o;
            }
        }
    }
}

extern "C" void kernel_launch(void* const* d_in, const int* in_sizes, int n_in,
                              void* d_out, int out_size, void* d_ws, size_t ws_size,
                              hipStream_t stream) {
    const float* x     = (const float*)d_in[0];
    const float* ln_g  = (const float*)d_in[1];
    const float* ln_b  = (const float*)d_in[2];
    const float* uv_W  = (const float*)d_in[3];
    const float* uv_b  = (const float*)d_in[4];
    const float* g_qk  = (const float*)d_in[5];
    const float* b_qk  = (const float*)d_in[6];
    const float* w_rel = (const float*)d_in[7];
    const float* o_W   = (const float*)d_in[8];
    const float* o_b   = (const float*)d_in[9];
    float* out = (float*)d_out;

    char* ws = (char*)d_ws;
    size_t off = 0;
    auto alloc = [&](size_t bytes) {
        void* p = ws + off;
        off += (bytes + 255) & ~(size_t)255;
        return p;
    };
    unsigned short* uvWT = (unsigned short*)alloc(3200ll * 768 * 2);
    unsigned short* oWT  = (unsigned short*)alloc(832ll * 1536 * 2);   // 768 + 64 pad rows
    unsigned short* xn   = (unsigned short*)alloc(16384ll * 768 * 2);
    unsigned short* u    = (unsigned short*)alloc(16384ll * 1536 * 2);
    unsigned short* vT   = (unsigned short*)alloc(32ll * 1600 * 512 * 2);  // +64 pad/batch
    unsigned short* q    = (unsigned short*)alloc(32ll * 512 * 128 * 2);
    unsigned short* k    = (unsigned short*)alloc((32ll * 512 + 128) * 128 * 2);  // +128 pad
    unsigned short* P     = xn;  // alias: xn dead after UV+bS kernels
    unsigned short* gated = u;   // alias: same-thread read-then-write

    // fused convT(uv_W) + convT(o_W) + LayerNorm
    k_pre<<<19936, 256, 0, stream>>>(uv_W, uvWT, o_W, oWT, x, ln_g, ln_b, xn);
    // UV: u | vT (N=3072 -> 768 blocks = exactly 3 rounds; NF=4)
    k8<10, 1, 12, 4><<<dim3(12, 64), 512, 0, stream>>>(
        xn, uvWT, 0, 0, (void*)u, (void*)vT, nullptr, (const void*)uv_b);
    // bS + rope fused: 256 blocks = 1 round -> q,k
    k_bs<<<256, 256, 0, stream>>>(xn, uvWT + 3072ll * 768, uv_b + 3072,
                                  g_qk, b_qk, q, k);
    // QK^T -> P: 256x128 tiles (NT=2, NF=2) -> 256 blocks = 1 round
    k8<1, 2, 2, 2><<<dim3(4, 2, 32), 512, 0, stream>>>(
        q, k, 512ll * 128, 512ll * 128, (void*)P, (void*)w_rel, nullptr, nullptr);
    // PV gated by u: 256x192 tiles -> 512 blocks = exactly 2 rounds
    k8<2, 2, 8, 3><<<dim3(8, 2, 32), 512, 0, stream>>>(
        P, vT, 512ll * 512, 1600ll * 512, (void*)gated, (void*)u, nullptr, nullptr);
    // out: 256x192 tiles -> 256 blocks = exactly 1 round
    k8<3, 1, 24, 3><<<dim3(4, 64), 512, 0, stream>>>(
        gated, oWT, 0, 0, (void*)out, (void*)o_b, (void*)x, nullptr);
}